// Round 4
// baseline (475.271 us; speedup 1.0000x reference)
//
#include <hip/hip_runtime.h>
#include <hip/hip_bf16.h>

// Problem constants
#define B_   16
#define C_   512
#define HW_  2304
#define NH_  8
#define HD_  64
#define SCALE_ 0.125f

typedef __bf16 bf16x8 __attribute__((ext_vector_type(8)));
typedef __bf16 bf16x4 __attribute__((ext_vector_type(4)));
typedef float  f32x4  __attribute__((ext_vector_type(4)));

#define MFMA16(a, b, c) __builtin_amdgcn_mfma_f32_16x16x32_bf16((a), (b), (c), 0, 0, 0)

// async global->LDS, 16B/lane; LDS dest = wave-uniform base + lane*16
__device__ __forceinline__ void gload_lds16(const void* g, void* l) {
    __builtin_amdgcn_global_load_lds(
        (const __attribute__((address_space(1))) unsigned int*)g,
        (__attribute__((address_space(3))) unsigned int*)l, 16, 0, 0);
}

// ---------------------------------------------------------------------------
// prep: z<48: transpose+convert input p=z>>4, batch b=z&15:
//             X[b][c][hw] fp32 -> XT_p[b][hw][c] bf16
//       z==48: convert 4 weight matrices fp32 -> bf16 (128 of 144 xy-blocks)
// ---------------------------------------------------------------------------
__global__ __launch_bounds__(256) void prep(
    const float* __restrict__ qf, const float* __restrict__ kf, const float* __restrict__ vf,
    __bf16* __restrict__ XTq, __bf16* __restrict__ XTk, __bf16* __restrict__ XTv,
    const float* __restrict__ Wq, const float* __restrict__ Wk,
    const float* __restrict__ Wv, const float* __restrict__ Wo,
    __bf16* __restrict__ Wb)
{
    const int t = threadIdx.x;
    if (blockIdx.z == 48) {
        const int bid = blockIdx.y * 18 + blockIdx.x;
        if (bid < 128) {
            const int wsel = bid >> 5;                    // 0..3
            const float* W = (wsel == 0) ? Wq : (wsel == 1) ? Wk : (wsel == 2) ? Wv : Wo;
            __bf16* D = Wb + wsel * 262144;
            const int off = (bid & 31) * 8192 + t * 32;
            #pragma unroll
            for (int c = 0; c < 4; ++c) {
                const float4 f0 = *(const float4*)&W[off + c * 8];
                const float4 f1 = *(const float4*)&W[off + c * 8 + 4];
                bf16x8 o;
                o[0] = (__bf16)f0.x; o[1] = (__bf16)f0.y; o[2] = (__bf16)f0.z; o[3] = (__bf16)f0.w;
                o[4] = (__bf16)f1.x; o[5] = (__bf16)f1.y; o[6] = (__bf16)f1.z; o[7] = (__bf16)f1.w;
                *(bf16x8*)&D[off + c * 8] = o;
            }
        }
        return;
    }
    const int p = blockIdx.z >> 4;
    const int b = blockIdx.z & 15;
    const float* X = ((p == 0) ? qf : (p == 1) ? kf : vf) + (size_t)b * C_ * HW_;
    __bf16* XT = ((p == 0) ? XTq : (p == 1) ? XTk : XTv) + (size_t)b * HW_ * C_;

    const int c0 = blockIdx.y * 64;
    const int h0 = blockIdx.x * 128;

    __shared__ float Ts[64 * 129];

    #pragma unroll
    for (int pp = 0; pp < 8; ++pp) {
        const int c  = pp * 8 + (t >> 5);
        const int hg = (t & 31) * 4;
        const float4 v = *(const float4*)&X[(size_t)(c0 + c) * HW_ + h0 + hg];
        Ts[c * 129 + hg + 0] = v.x;
        Ts[c * 129 + hg + 1] = v.y;
        Ts[c * 129 + hg + 2] = v.z;
        Ts[c * 129 + hg + 3] = v.w;
    }
    __syncthreads();
    #pragma unroll
    for (int pp = 0; pp < 4; ++pp) {
        const int hw = pp * 32 + (t >> 3);
        const int g  = (t & 7) * 8;
        bf16x8 o;
        #pragma unroll
        for (int e = 0; e < 8; ++e)
            o[e] = (__bf16)Ts[(g + e) * 129 + hw];
        *(bf16x8*)&XT[(size_t)(h0 + hw) * C_ + c0 + g] = o;
    }
}

// ---------------------------------------------------------------------------
// GEMM core: D[m][n] = sum_k A[m0+m][k] * Bm[n0+n][k]  (+bias), K=512.
// Both operands row-major k-contiguous (row stride 512), staged via swizzled
// global_load_lds dwordx4 (granule (lane&7)^(lane>>3); frag read granule
// (kk*4+q)^(l16&7) -> 2 lanes/bank, conflict-free).
// BIAS_N=false: +bias[m]; true: +bias[n].
// ---------------------------------------------------------------------------
template <bool BIAS_N, typename OUT_T>
__device__ __forceinline__ void gemm_core(
    const __bf16* __restrict__ A, const __bf16* __restrict__ Bm,
    const float* __restrict__ bias, OUT_T* __restrict__ Y, int ldY,
    int m0, int n0)
{
    __shared__ __align__(16) __bf16 As[128 * 64];
    __shared__ __align__(16) __bf16 Bs[128 * 64];

    const int t = threadIdx.x;
    const int w = t >> 6, lane = t & 63, l16 = lane & 15, q = lane >> 4;
    const int wm = w >> 1, wn = w & 1;
    const int sr = lane >> 3;
    const int sg = ((lane & 7) ^ (lane >> 3)) * 8;

    f32x4 acc[4][4] = {};

    for (int ks = 0; ks < 8; ++ks) {
        const int k0 = ks * 64;
        __syncthreads();
        #pragma unroll
        for (int p = 0; p < 4; ++p) {
            const int rb = p * 32 + w * 8;               // wave-uniform
            gload_lds16(&A [(size_t)(m0 + rb + sr) * C_ + k0 + sg], &As[rb * 64]);
            gload_lds16(&Bm[(size_t)(n0 + rb + sr) * C_ + k0 + sg], &Bs[rb * 64]);
        }
        __syncthreads();
        #pragma unroll
        for (int kk = 0; kk < 2; ++kk) {
            const int sw = ((kk * 4 + q) ^ (l16 & 7)) * 8;
            bf16x8 af[4], bfr[4];
            #pragma unroll
            for (int mi = 0; mi < 4; ++mi)
                af[mi] = *(bf16x8*)&As[(wm * 64 + mi * 16 + l16) * 64 + sw];
            #pragma unroll
            for (int ni = 0; ni < 4; ++ni)
                bfr[ni] = *(bf16x8*)&Bs[(wn * 64 + ni * 16 + l16) * 64 + sw];
            #pragma unroll
            for (int mi = 0; mi < 4; ++mi)
                #pragma unroll
                for (int ni = 0; ni < 4; ++ni)
                    acc[mi][ni] = MFMA16(af[mi], bfr[ni], acc[mi][ni]);
        }
    }

    float bnv[4];
    if (BIAS_N) {
        #pragma unroll
        for (int ni = 0; ni < 4; ++ni)
            bnv[ni] = bias[n0 + wn * 64 + ni * 16 + l16];
    }
    #pragma unroll
    for (int mi = 0; mi < 4; ++mi) {
        #pragma unroll
        for (int r = 0; r < 4; ++r) {
            const int m = m0 + wm * 64 + mi * 16 + q * 4 + r;
            const float bm = BIAS_N ? 0.f : bias[m];
            #pragma unroll
            for (int ni = 0; ni < 4; ++ni) {
                const int n = n0 + wn * 64 + ni * 16 + l16;
                const float v = acc[mi][ni][r] + (BIAS_N ? bnv[ni] : bm);
                Y[(size_t)m * ldY + n] = (OUT_T)v;
            }
        }
    }
}

// ---------------------------------------------------------------------------
// gemm_all: y encodes (p = y>>4, b = y&15).
//   p=0/1: Q/K[b][o][hw] = Wb_p . XT_p[b]   (M=512, N=2304, ld=2304, bias[m])
//   p=2  : VT[b][hw][o] = XT_v[b] . Wb_v^T  (M=2304, N=512, ld=512, bias[n])
// ---------------------------------------------------------------------------
__global__ __launch_bounds__(256) void gemm_all(
    const __bf16* __restrict__ XTq, const __bf16* __restrict__ XTk,
    const __bf16* __restrict__ XTv, const __bf16* __restrict__ Wb,
    const float* __restrict__ bq, const float* __restrict__ bk,
    const float* __restrict__ bv,
    __bf16* __restrict__ Qw, __bf16* __restrict__ Kw, __bf16* __restrict__ VTw)
{
    const int x = blockIdx.x;       // 0..71
    const int p = blockIdx.y >> 4;
    const int b = blockIdx.y & 15;
    if (p == 2) {
        const int m0 = (x % 18) * 128;
        const int n0 = (x / 18) * 128;
        gemm_core<true, __bf16>(XTv + (size_t)b * HW_ * C_, Wb + 2 * 262144,
                                bv, VTw + (size_t)b * HW_ * C_, C_, m0, n0);
    } else {
        const int m0 = (x & 3) * 128;
        const int n0 = (x >> 2) * 128;
        const __bf16* XT = (p == 0) ? XTq : XTk;
        __bf16* Y = (p == 0) ? Qw : Kw;
        gemm_core<false, __bf16>(Wb + p * 262144, XT + (size_t)b * HW_ * C_,
                                 (p == 0) ? bq : bk,
                                 Y + (size_t)b * C_ * HW_, HW_, m0, n0);
    }
}

// ---------------------------------------------------------------------------
// Scores partial (split-K 6): Sp[kc][bn][64][64], K-chunk = 384.
// ---------------------------------------------------------------------------
__global__ __launch_bounds__(256) void attn_scores_part(
    const __bf16* __restrict__ Qw, const __bf16* __restrict__ Kw,
    float* __restrict__ Sp)
{
    const int bn  = blockIdx.x;
    const int kcs = blockIdx.y;
    const __bf16* Qb = Qw + (size_t)bn * 64 * HW_;
    const __bf16* Kb = Kw + (size_t)bn * 64 * HW_;

    __shared__ __align__(16) __bf16 Qs[64 * 64];
    __shared__ __align__(16) __bf16 Ks[64 * 64];

    const int t    = threadIdx.x;
    const int w    = t >> 6;
    const int lane = t & 63;
    const int l16  = lane & 15;
    const int q    = lane >> 4;
    const int sr   = lane >> 3;
    const int sg   = ((lane & 7) ^ (lane >> 3)) * 8;

    f32x4 acc[4] = {};

    for (int it = 0; it < 6; ++it) {
        const int k0 = kcs * 384 + it * 64;
        __syncthreads();
        #pragma unroll
        for (int p = 0; p < 2; ++p) {
            const int rb = w * 16 + p * 8;
            gload_lds16(&Qb[(size_t)(rb + sr) * HW_ + k0 + sg], &Qs[rb * 64]);
            gload_lds16(&Kb[(size_t)(rb + sr) * HW_ + k0 + sg], &Ks[rb * 64]);
        }
        __syncthreads();
        #pragma unroll
        for (int kk = 0; kk < 2; ++kk) {
            const int sw = ((kk * 4 + q) ^ (l16 & 7)) * 8;
            const bf16x8 a = *(bf16x8*)&Qs[(w * 16 + l16) * 64 + sw];
            #pragma unroll
            for (int ni = 0; ni < 4; ++ni) {
                const bf16x8 bb = *(bf16x8*)&Ks[(ni * 16 + l16) * 64 + sw];
                acc[ni] = MFMA16(a, bb, acc[ni]);
            }
        }
    }

    float* S = Sp + ((size_t)kcs * 128 + bn) * 4096;
    #pragma unroll
    for (int r = 0; r < 4; ++r)
        #pragma unroll
        for (int ni = 0; ni < 4; ++ni)
            S[(w * 16 + q * 4 + r) * 64 + ni * 16 + l16] = acc[ni][r];
}

// ---------------------------------------------------------------------------
// Softmax reduce: sum 6 partials, scale, softmax/row, write P bf16.
// ---------------------------------------------------------------------------
__global__ __launch_bounds__(256) void softmax_reduce(
    const float* __restrict__ Sp, __bf16* __restrict__ Pw)
{
    const int bn = blockIdx.x;
    const int t  = threadIdx.x;
    const int r  = t >> 2;
    const int c0 = (t & 3) * 16;

    float v[16];
    #pragma unroll
    for (int j = 0; j < 16; ++j) v[j] = 0.f;
    #pragma unroll
    for (int kc = 0; kc < 6; ++kc) {
        const float* s = Sp + ((size_t)kc * 128 + bn) * 4096 + r * 64 + c0;
        #pragma unroll
        for (int j4 = 0; j4 < 4; ++j4) {
            const float4 f = *(const float4*)&s[j4 * 4];
            v[j4 * 4 + 0] += f.x; v[j4 * 4 + 1] += f.y;
            v[j4 * 4 + 2] += f.z; v[j4 * 4 + 3] += f.w;
        }
    }
    float mx = -1e30f;
    #pragma unroll
    for (int j = 0; j < 16; ++j) { v[j] *= SCALE_; mx = fmaxf(mx, v[j]); }
    mx = fmaxf(mx, __shfl_xor(mx, 1));
    mx = fmaxf(mx, __shfl_xor(mx, 2));
    float s = 0.f;
    #pragma unroll
    for (int j = 0; j < 16; ++j) { v[j] = __expf(v[j] - mx); s += v[j]; }
    s += __shfl_xor(s, 1);
    s += __shfl_xor(s, 2);
    const float inv = 1.f / s;
    bf16x8 o0, o1;
    #pragma unroll
    for (int j = 0; j < 8; ++j) {
        o0[j] = (__bf16)(v[j] * inv);
        o1[j] = (__bf16)(v[8 + j] * inv);
    }
    *(bf16x8*)&Pw[(size_t)bn * 4096 + r * 64 + c0]     = o0;
    *(bf16x8*)&Pw[(size_t)bn * 4096 + r * 64 + c0 + 8] = o1;
}

// ---------------------------------------------------------------------------
// O = P @ V -> AOT[b][hw][c] bf16.  Grid (9 d-slabs, 128 bn).
// P (A-operand, [h][k] k-contig) and VT (B-operand, [d][k] k-contig) both
// staged via swizzled global_load_lds — no VALU staging, single barrier.
// ---------------------------------------------------------------------------
__global__ __launch_bounds__(256) void attn_pv(
    const __bf16* __restrict__ Pw, const __bf16* __restrict__ VTw,
    __bf16* __restrict__ AOT)
{
    const int dsl = blockIdx.x;
    const int bn  = blockIdx.y;
    const int bb  = bn >> 3;
    const int nh  = bn & 7;
    const int t    = threadIdx.x;
    const int w    = t >> 6;
    const int lane = t & 63;
    const int l16  = lane & 15;
    const int q    = lane >> 4;
    const int sr   = lane >> 3;
    const int sg   = ((lane & 7) ^ (lane >> 3)) * 8;

    __shared__ __align__(16) __bf16 Ps[64 * 64];
    __shared__ __align__(16) __bf16 Vs[256 * 64];

    // stage P (shared across waves)
    #pragma unroll
    for (int p = 0; p < 2; ++p) {
        const int rb = w * 16 + p * 8;
        gload_lds16(&Pw[(size_t)bn * 4096 + (rb + sr) * 64 + sg], &Ps[rb * 64]);
    }
    // stage this wave's 64 d-rows of VT
    const __bf16* Vbase = VTw + ((size_t)bb * HW_ + dsl * 256) * C_ + nh * 64;
    #pragma unroll
    for (int p = 0; p < 8; ++p) {
        const int rb = w * 64 + p * 8;
        gload_lds16(&Vbase[(size_t)(rb + sr) * C_ + sg], &Vs[rb * 64]);
    }
    __syncthreads();

    f32x4 acc[4][4] = {};
    #pragma unroll
    for (int kk = 0; kk < 2; ++kk) {
        const int sw = ((kk * 4 + q) ^ (l16 & 7)) * 8;
        bf16x8 af[4], bfr[4];
        #pragma unroll
        for (int mi = 0; mi < 4; ++mi)
            af[mi] = *(bf16x8*)&Ps[(mi * 16 + l16) * 64 + sw];
        #pragma unroll
        for (int ni = 0; ni < 4; ++ni)
            bfr[ni] = *(bf16x8*)&Vs[(w * 64 + ni * 16 + l16) * 64 + sw];
        #pragma unroll
        for (int mi = 0; mi < 4; ++mi)
            #pragma unroll
            for (int ni = 0; ni < 4; ++ni)
                acc[mi][ni] = MFMA16(af[mi], bfr[ni], acc[mi][ni]);
    }

    #pragma unroll
    for (int mi = 0; mi < 4; ++mi)
        #pragma unroll
        for (int ni = 0; ni < 4; ++ni) {
            const int d = dsl * 256 + w * 64 + ni * 16 + l16;
            bf16x4 o;
            #pragma unroll
            for (int r = 0; r < 4; ++r) o[r] = (__bf16)acc[mi][ni][r];
            *(bf16x4*)&AOT[((size_t)bb * HW_ + d) * C_ + nh * 64 + mi * 16 + q * 4] = o;
        }
}

// ---------------------------------------------------------------------------
// Output projection: out[b][o][hw] = Wo_b . AOT[b] + bo.
// ---------------------------------------------------------------------------
__global__ __launch_bounds__(256) void proj_out(
    const __bf16* __restrict__ AOT, const __bf16* __restrict__ WoB,
    const float* __restrict__ bo, float* __restrict__ out)
{
    const int x = blockIdx.x;
    const int b = blockIdx.y;
    const int m0 = (x & 3) * 128;
    const int n0 = (x >> 2) * 128;
    gemm_core<false, float>(WoB, AOT + (size_t)b * HW_ * C_, bo,
                            out + (size_t)b * C_ * HW_, HW_, m0, n0);
}

// ---------------------------------------------------------------------------
extern "C" void kernel_launch(void* const* d_in, const int* in_sizes, int n_in,
                              void* d_out, int out_size, void* d_ws, size_t ws_size,
                              hipStream_t stream)
{
    (void)in_sizes; (void)n_in; (void)out_size; (void)ws_size;
    const float* qf = (const float*)d_in[0];
    const float* kf = (const float*)d_in[1];
    const float* vf = (const float*)d_in[2];
    const float* Wq = (const float*)d_in[3];
    const float* bq = (const float*)d_in[4];
    const float* Wk = (const float*)d_in[5];
    const float* bk = (const float*)d_in[6];
    const float* Wv = (const float*)d_in[7];
    const float* bv = (const float*)d_in[8];
    const float* Wo = (const float*)d_in[9];
    const float* bo = (const float*)d_in[10];

    const size_t QE = (size_t)B_ * C_ * HW_;   // 18,874,368 elems (36 MiB bf16)
    // d_out (72 MiB) doubles as scratch for XT_q, XT_k (exact fit); dead
    // before proj_out overwrites it.  ws (>=216 MiB per fill counter):
    //   [0, QE)        XT_v  -> Sp (12 MiB) -> AOT      (stream-serial)
    //   [QE, 2QE)      Qw
    //   [2QE, 3QE)     Kw
    //   [3QE, 4QE)     VTw   ([b][hw][c], V-transposed)
    //   [4QE, +1M)     Wb    (4 x 262144 bf16 weights)
    //   [+1M, +1.5M)   Pw
    __bf16* XTq = (__bf16*)d_out;
    __bf16* XTk = XTq + QE;
    __bf16* base = (__bf16*)d_ws;
    __bf16* XTv = base;
    float*  Sp  = (float*)base;                // 6*128*4096*4 = 12.6 MB
    __bf16* AOT = base;
    __bf16* Qw  = base + QE;
    __bf16* Kw  = base + 2 * QE;
    __bf16* VTw = base + 3 * QE;
    __bf16* Wb  = base + 4 * QE;               // 2 MiB
    __bf16* Pw  = Wb + 4 * 262144;             // 1 MiB

    prep            <<<dim3(18, 8, 49), 256, 0, stream>>>(qf, kf, vf, XTq, XTk, XTv,
                                                          Wq, Wk, Wv, Wo, Wb);
    gemm_all        <<<dim3(72, 48),    256, 0, stream>>>(XTq, XTk, XTv, Wb,
                                                          bq, bk, bv, Qw, Kw, VTw);
    attn_scores_part<<<dim3(128, 6),    256, 0, stream>>>(Qw, Kw, Sp);
    softmax_reduce  <<<dim3(128),       256, 0, stream>>>(Sp, Pw);
    attn_pv         <<<dim3(9, 128),    256, 0, stream>>>(Pw, VTw, AOT);
    proj_out        <<<dim3(72, 16),    256, 0, stream>>>(AOT, Wb + 3 * 262144, bo,
                                                          (float*)d_out);
}